// Round 8
// baseline (745.757 us; speedup 1.0000x reference)
//
#include <hip/hip_runtime.h>
#include <hip/hip_fp16.h>

#define N_NODES 50000
#define N_EDGES 800000
#define N_OBS   4
#define HID     64
#define K_HOPS  5
#define ROW     (N_OBS * HID)   // 256 elements per node
#define NSCAN_BLKS ((N_NODES + 1023) / 1024)   // 49
#define NSLICE  8               // hid sliced 8x8: slice-row = 4 obs x 8 hid = 32 f16 = 64B
#define NBUCKET 256

typedef _Float16 f16x8 __attribute__((ext_vector_type(8)));
typedef _Float16 f16x4 __attribute__((ext_vector_type(4)));
typedef float    f32x4 __attribute__((ext_vector_type(4)));

// ---------------------------------------------------------------- zero
__global__ void zero_kernel(int* __restrict__ p, int n) {
    int i = blockIdx.x * blockDim.x + threadIdx.x;
    if (i < n) p[i] = 0;
}

// ---------------------------------------------------------------- histogram of dst
__global__ void hist_kernel(const int* __restrict__ dst, int* __restrict__ cnt) {
    int e = blockIdx.x * blockDim.x + threadIdx.x;
    if (e < N_EDGES) atomicAdd(&cnt[dst[e]], 1);
}

// ---------------------------------------------------------------- scan pass 1: per-block sums
__global__ __launch_bounds__(1024) void scan1_kernel(const int* __restrict__ counts,
                                                     int* __restrict__ bsum) {
    __shared__ int wsum[16];
    const int t = threadIdx.x, lane = t & 63, wid = t >> 6;
    int i = blockIdx.x * 1024 + t;
    int x = (i < N_NODES) ? counts[i] : 0;
    #pragma unroll
    for (int off = 32; off > 0; off >>= 1) x += __shfl_xor(x, off);
    if (lane == 0) wsum[wid] = x;
    __syncthreads();
    if (t == 0) {
        int s = 0;
        #pragma unroll
        for (int j = 0; j < 16; ++j) s += wsum[j];
        bsum[blockIdx.x] = s;
    }
}

// ---------------------------------------------------------------- scan pass 2: exclusive scan of block sums (1 wave)
__global__ void scan2_kernel(int* __restrict__ bsum) {
    const int t = threadIdx.x;   // 64 threads
    int v = (t < NSCAN_BLKS) ? bsum[t] : 0;
    int x = v;
    #pragma unroll
    for (int off = 1; off < 64; off <<= 1) {
        int y = __shfl_up(x, off);
        if (t >= off) x += y;
    }
    if (t < NSCAN_BLKS) bsum[t] = x - v;   // exclusive
}

// ---------------------------------------------------------------- scan pass 3: full offsets + cursor
__global__ __launch_bounds__(1024) void scan3_kernel(const int* __restrict__ counts,
                                                     const int* __restrict__ bsum,
                                                     int* __restrict__ offsets,
                                                     int* __restrict__ cursor) {
    __shared__ int wsum[16];
    __shared__ int wpre[16];
    const int t = threadIdx.x, lane = t & 63, wid = t >> 6;
    int i = blockIdx.x * 1024 + t;
    int v = (i < N_NODES) ? counts[i] : 0;
    int x = v;
    #pragma unroll
    for (int off = 1; off < 64; off <<= 1) {
        int y = __shfl_up(x, off);
        if (lane >= off) x += y;
    }
    if (lane == 63) wsum[wid] = x;
    __syncthreads();
    if (t < 16) {
        int p = 0;
        for (int j = 0; j < t; ++j) p += wsum[j];
        wpre[t] = p;
    }
    __syncthreads();
    int base = bsum[blockIdx.x];
    int incl = base + x + wpre[wid];
    if (i < N_NODES) {
        offsets[i + 1] = incl;
        cursor[i]      = incl - v;
    }
    if (i == 0) offsets[0] = 0;
}

// ---------------------------------------------------------------- degree histogram (256 buckets)
__global__ void dhist_kernel(const int* __restrict__ cnt, int* __restrict__ dh) {
    int n = blockIdx.x * blockDim.x + threadIdx.x;
    if (n < N_NODES) {
        int b = cnt[n]; if (b > NBUCKET - 1) b = NBUCKET - 1;
        atomicAdd(&dh[b], 1);
    }
}

// ---------------------------------------------------------------- exclusive scan of 256 buckets (1 block)
__global__ __launch_bounds__(256) void dscan_kernel(const int* __restrict__ dh,
                                                    int* __restrict__ ds) {
    __shared__ int wsum[4];
    __shared__ int wpre[4];
    const int t = threadIdx.x, lane = t & 63, w = t >> 6;
    int v = dh[t];
    int x = v;
    #pragma unroll
    for (int off = 1; off < 64; off <<= 1) {
        int y = __shfl_up(x, off);
        if (lane >= off) x += y;
    }
    if (lane == 63) wsum[w] = x;
    __syncthreads();
    if (t < 4) {
        int p = 0;
        for (int j = 0; j < t; ++j) p += wsum[j];
        wpre[t] = p;
    }
    __syncthreads();
    ds[t] = x + wpre[w] - v;   // exclusive
}

// ---------------------------------------------------------------- scatter nodes into degree-sorted order
__global__ void dscatter_kernel(const int* __restrict__ cnt, int* __restrict__ ds,
                                int* __restrict__ perm) {
    int n = blockIdx.x * blockDim.x + threadIdx.x;
    if (n < N_NODES) {
        int b = cnt[n]; if (b > NBUCKET - 1) b = NBUCKET - 1;
        int p = atomicAdd(&ds[b], 1);
        perm[p] = n;
    }
}

// ---------------------------------------------------------------- scatter edges into CSR order, packed {f16 w | u16 src}
__global__ void scatter_kernel(const int* __restrict__ src, const int* __restrict__ dst,
                               const float* __restrict__ w, int* __restrict__ cursor,
                               unsigned int* __restrict__ ecmp) {
    int e = blockIdx.x * blockDim.x + threadIdx.x;
    if (e < N_EDGES) {
        int d = dst[e];
        int p = atomicAdd(&cursor[d], 1);
        __half hw = __float2half(w[e]);
        ecmp[p] = ((unsigned int)__half_as_ushort(hw) << 16) | (unsigned int)src[e];
    }
}

// ---------------------------------------------------------------- lift into sliced X[s][n][o][h3] f16
__global__ void lift_kernel(const float* __restrict__ nodes, const float* __restrict__ Wl,
                            const float* __restrict__ bl, __half* __restrict__ Xs) {
    int i = blockIdx.x * blockDim.x + threadIdx.x;   // 8B chunk = 4 f16
    const int total = N_NODES * ROW / 4;
    if (i >= total) return;
    int n   = i >> 6;
    int rem = i & 63;
    int o   = rem >> 4;
    int h4  = rem & 15;          // h = h4*4 .. +3
    int s   = h4 >> 1;
    int h3  = (h4 & 1) * 4;
    float sc = nodes[n * 4 + o];
    float4 wl = ((const float4*)Wl)[h4];
    float4 b  = ((const float4*)bl)[h4];
    f16x4 st;
    st[0] = (_Float16)(sc * wl.x + b.x);
    st[1] = (_Float16)(sc * wl.y + b.y);
    st[2] = (_Float16)(sc * wl.z + b.z);
    st[3] = (_Float16)(sc * wl.w + b.w);
    *(f16x4*)(Xs + (((size_t)s * N_NODES + n) * 4 + o) * 8 + h3) = st;
}

// ---------------------------------------------------------------- pack W_hop into MFMA B-fragment order (f16)
__global__ void packW_kernel(const float* __restrict__ W, _Float16* __restrict__ Bp) {
    int i = blockIdx.x * 256 + threadIdx.x;   // 0..4095
    if (i >= 4096) return;
    int j  = i & 7;
    int l  = (i >> 3) & 63;
    int ks = (i >> 9) & 1;
    int w  = i >> 10;
    int k   = ks * 32 + ((j >> 2) * 16) + ((l >> 4) * 4) + (j & 3);
    int col = w * 16 + (l & 15);
    Bp[i] = (_Float16)W[k * 64 + col];
}

// ---------------------------------------------------------------- pass 1: sliced gather, direct edge loads.
// slice = blockIdx & 7 (XCD affinity; FETCH floor proven in R5/R7).
// 4 lanes per node (16B f16x8 each = 64B slice-row), 16 nodes per wave,
// 64 nodes per block. Nodes taken in degree-sorted order (perm) so the
// wave's 16 nodes have near-equal degree. Edge words loaded directly
// (4 same-address lanes -> HW broadcast); unroll-2 with w=0 padding.
__global__ __launch_bounds__(256) void gather_kernel(const int* __restrict__ offsets,
                                                     const int* __restrict__ perm,
                                                     const unsigned int* __restrict__ ecmp,
                                                     const __half* __restrict__ Xs,
                                                     __half* __restrict__ Ag) {
    const int t = threadIdx.x;
    const int wid = t >> 6, lane = t & 63;
    const int s = blockIdx.x & 7;
    const int g = blockIdx.x >> 3;           // node-block 0..781
    const int grp = lane >> 2;               // node within wave (0..15)
    const int el  = lane & 3;                // 16B chunk of the 64B slice-row
    const int pos = (g * 4 + wid) * 16 + grp;           // sorted position
    const int pcl = (pos < N_NODES) ? pos : N_NODES - 1;
    const int n_orig = perm[pcl];
    const int sN = offsets[n_orig];
    const int m = (pos < N_NODES) ? (offsets[n_orig + 1] - sN) : 0;
    const __half* Xb = Xs + (size_t)s * ((size_t)N_NODES * 32);

    float acc[8] = {0.f, 0.f, 0.f, 0.f, 0.f, 0.f, 0.f, 0.f};

    for (int q = 0; q < m; q += 2) {
        int e0 = sN + q;
        int e1 = sN + q + 1; if (e1 > N_EDGES - 1) e1 = N_EDGES - 1;
        unsigned int p0 = ecmp[e0];
        unsigned int p1 = ecmp[e1];
        bool a1 = (q + 1 < m);
        float w0 = __half2float(__ushort_as_half((unsigned short)(p0 >> 16)));
        float w1 = a1 ? __half2float(__ushort_as_half((unsigned short)(p1 >> 16))) : 0.f;
        int s0 = (int)(p0 & 0xffffu);
        int s1 = (int)(p1 & 0xffffu);
        f16x8 v0 = *(const f16x8*)(Xb + s0 * 32 + el * 8);
        f16x8 v1 = *(const f16x8*)(Xb + s1 * 32 + el * 8);
        #pragma unroll
        for (int k = 0; k < 8; ++k) acc[k] += w0 * (float)v0[k];
        #pragma unroll
        for (int k = 0; k < 8; ++k) acc[k] += w1 * (float)v1[k];
    }

    if (pos < N_NODES) {
        f16x8 st;
        #pragma unroll
        for (int k = 0; k < 8; ++k) st[k] = (_Float16)acc[k];
        *(f16x8*)(Ag + ((size_t)s * N_NODES + pos) * 32 + el * 8) = st;
    }
}

// ---------------------------------------------------------------- pass 2: GEMM + bias + ReLU
// 16 sorted positions (64 rows) per block; agg read densely at sorted
// positions; outputs scatter-written through perm. 8 MFMA per wave.
template<int LAST>
__global__ __launch_bounds__(256) void mm_kernel(const __half* __restrict__ Ag,
                                                 const int* __restrict__ perm,
                                                 const _Float16* __restrict__ Bp,
                                                 const float* __restrict__ bias,
                                                 __half* __restrict__ Xs,
                                                 float* __restrict__ Fout) {
    __shared__ _Float16 As[64][72];
    __shared__ int psh[16];
    const int t = threadIdx.x;
    const int wid = t >> 6, lane = t & 63;
    const int n0 = blockIdx.x * 16;

    if (t < 16) psh[t] = perm[n0 + t];
    // stage 16 nodes x 8 slices x 64B = 8KB
    #pragma unroll
    for (int it = 0; it < 2; ++it) {
        int c = t + 256 * it;      // 16B chunk id 0..511
        int s = c >> 6;
        int m = c & 63;            // 16 nodes x 4 chunks
        int nl = m >> 2, o = m & 3;
        f16x8 v = *(const f16x8*)(Ag + (((size_t)s * N_NODES + n0 + nl) * 4 + o) * 8);
        *(f16x8*)&As[nl * 4 + o][s * 8] = v;
    }
    __syncthreads();

    const int r15 = lane & 15, gq = lane >> 4;
    f16x8 b0 = *(const f16x8*)(Bp + ((size_t)(wid * 2 + 0) * 64 + lane) * 8);
    f16x8 b1 = *(const f16x8*)(Bp + ((size_t)(wid * 2 + 1) * 64 + lane) * 8);
    const float bv = bias[wid * 16 + r15];
    const int h = wid * 16 + r15;

    #pragma unroll
    for (int rg = 0; rg < 4; ++rg) {
        const int row = rg * 16 + r15;
        f16x8 a0, a1;
        ((f16x4*)&a0)[0] = *(const f16x4*)&As[row][ 0 + 4 * gq];
        ((f16x4*)&a0)[1] = *(const f16x4*)&As[row][16 + 4 * gq];
        ((f16x4*)&a1)[0] = *(const f16x4*)&As[row][32 + 4 * gq];
        ((f16x4*)&a1)[1] = *(const f16x4*)&As[row][48 + 4 * gq];
        f32x4 c4 = {0.f, 0.f, 0.f, 0.f};
        c4 = __builtin_amdgcn_mfma_f32_16x16x32_f16(a0, b0, c4, 0, 0, 0);
        c4 = __builtin_amdgcn_mfma_f32_16x16x32_f16(a1, b1, c4, 0, 0, 0);
        #pragma unroll
        for (int j = 0; j < 4; ++j) {
            int r_abs = rg * 16 + gq * 4 + j;   // output row (local)
            int nl = r_abs >> 2, o = r_abs & 3;
            int pm = psh[nl];                   // original node id
            float v = fmaxf(c4[j] + bv, 0.f);
            if (LAST) {
                Fout[((size_t)pm * 4 + o) * 64 + h] = v;
            } else {
                int sl = h >> 3, h3 = h & 7;
                Xs[(((size_t)sl * N_NODES + pm) * 4 + o) * 8 + h3] = __float2half(v);
            }
        }
    }
}

// ---------------------------------------------------------------- launch
extern "C" void kernel_launch(void* const* d_in, const int* in_sizes, int n_in,
                              void* d_out, int out_size, void* d_ws, size_t ws_size,
                              hipStream_t stream) {
    const float* nodes   = (const float*)d_in[0];
    const int*   esrc    = (const int*)d_in[1];
    const int*   edst    = (const int*)d_in[2];
    const float* eweight = (const float*)d_in[3];
    const float* W_lift  = (const float*)d_in[4];
    const float* b_lift  = (const float*)d_in[5];
    const float* W_hop   = (const float*)d_in[6];
    const float* b_hop   = (const float*)d_in[7];

    char* ws = (char*)d_ws;
    __half*       X    = (__half*)(ws);                      // 25,600,000 B (sliced)
    __half*       AGG  = (__half*)(ws + 25600000);           // 25,600,000 B (sliced)
    unsigned int* ECMP = (unsigned int*)(ws + 51200000);     //  3,200,000 B
    int*          OFF  = (int*)(ws + 54400000);              //    200,064 B
    int*          CUR  = (int*)(ws + 54600064);              //    200,000 B
    int*          CNT  = (int*)(ws + 54800064);              //    200,000 B
    int*          BSUM = (int*)(ws + 55000064);              //        256 B
    _Float16*     BP   = (_Float16*)(ws + 55000320);         //      8,192 B
    int*          PERM = (int*)(ws + 55008512);              //    200,000 B
    int*          DH   = (int*)(ws + 55208512);              //      1,024 B
    int*          DS   = (int*)(ws + 55209536);              //      1,024 B

    // CSR build
    zero_kernel<<<(N_NODES + 255) / 256, 256, 0, stream>>>(CNT, N_NODES);
    zero_kernel<<<1, 256, 0, stream>>>(DH, NBUCKET);
    hist_kernel<<<(N_EDGES + 255) / 256, 256, 0, stream>>>(edst, CNT);
    scan1_kernel<<<NSCAN_BLKS, 1024, 0, stream>>>(CNT, BSUM);
    scan2_kernel<<<1, 64, 0, stream>>>(BSUM);
    scan3_kernel<<<NSCAN_BLKS, 1024, 0, stream>>>(CNT, BSUM, OFF, CUR);
    scatter_kernel<<<(N_EDGES + 255) / 256, 256, 0, stream>>>(esrc, edst, eweight, CUR, ECMP);

    // degree sort (256-bucket counting sort -> PERM)
    dhist_kernel<<<(N_NODES + 255) / 256, 256, 0, stream>>>(CNT, DH);
    dscan_kernel<<<1, 256, 0, stream>>>(DH, DS);
    dscatter_kernel<<<(N_NODES + 255) / 256, 256, 0, stream>>>(CNT, DS, PERM);

    // lift -> sliced f16 X ; pack W_hop -> MFMA B fragments
    lift_kernel<<<(N_NODES * ROW / 4 + 255) / 256, 256, 0, stream>>>(nodes, W_lift, b_lift, X);
    packW_kernel<<<16, 256, 0, stream>>>(W_hop, BP);

    // hops: sliced gather (pass 1) + GEMM (pass 2); X updated in place by pass 2
    const int gGrid  = ((N_NODES + 63) / 64) * NSLICE;   // 782 * 8 = 6256 (64 nodes/block)
    const int mmGrid = N_NODES / 16;                     // 3125
    for (int hop = 0; hop < K_HOPS; ++hop) {
        gather_kernel<<<gGrid, 256, 0, stream>>>(OFF, PERM, ECMP, X, AGG);
        if (hop == K_HOPS - 1) {
            mm_kernel<1><<<mmGrid, 256, 0, stream>>>(AGG, PERM, BP, b_hop, nullptr, (float*)d_out);
        } else {
            mm_kernel<0><<<mmGrid, 256, 0, stream>>>(AGG, PERM, BP, b_hop, X, nullptr);
        }
    }
}

// Round 9
// 355.386 us; speedup vs baseline: 2.0984x; 2.0984x over previous
//
#include <hip/hip_runtime.h>
#include <hip/hip_fp16.h>

#define N_NODES 50000
#define N_EDGES 800000
#define N_OBS   4
#define HID     64
#define K_HOPS  5
#define ROW     (N_OBS * HID)   // 256 elements per node
#define NSCAN_BLKS ((N_NODES + 1023) / 1024)   // 49

typedef _Float16 f16x8 __attribute__((ext_vector_type(8)));
typedef _Float16 f16x4 __attribute__((ext_vector_type(4)));
typedef float    f32x4 __attribute__((ext_vector_type(4)));

// ---------------------------------------------------------------- zero
__global__ void zero_kernel(int* __restrict__ p, int n) {
    int i = blockIdx.x * blockDim.x + threadIdx.x;
    if (i < n) p[i] = 0;
}

// ---------------------------------------------------------------- histogram of dst
__global__ void hist_kernel(const int* __restrict__ dst, int* __restrict__ cnt) {
    int e = blockIdx.x * blockDim.x + threadIdx.x;
    if (e < N_EDGES) atomicAdd(&cnt[dst[e]], 1);
}

// ---------------------------------------------------------------- scan pass 1: per-block sums
__global__ __launch_bounds__(1024) void scan1_kernel(const int* __restrict__ counts,
                                                     int* __restrict__ bsum) {
    __shared__ int wsum[16];
    const int t = threadIdx.x, lane = t & 63, wid = t >> 6;
    int i = blockIdx.x * 1024 + t;
    int x = (i < N_NODES) ? counts[i] : 0;
    #pragma unroll
    for (int off = 32; off > 0; off >>= 1) x += __shfl_xor(x, off);
    if (lane == 0) wsum[wid] = x;
    __syncthreads();
    if (t == 0) {
        int s = 0;
        #pragma unroll
        for (int j = 0; j < 16; ++j) s += wsum[j];
        bsum[blockIdx.x] = s;
    }
}

// ---------------------------------------------------------------- scan pass 2: exclusive scan of block sums (1 wave)
__global__ void scan2_kernel(int* __restrict__ bsum) {
    const int t = threadIdx.x;   // 64 threads
    int v = (t < NSCAN_BLKS) ? bsum[t] : 0;
    int x = v;
    #pragma unroll
    for (int off = 1; off < 64; off <<= 1) {
        int y = __shfl_up(x, off);
        if (t >= off) x += y;
    }
    if (t < NSCAN_BLKS) bsum[t] = x - v;   // exclusive
}

// ---------------------------------------------------------------- scan pass 3: full offsets + cursor
__global__ __launch_bounds__(1024) void scan3_kernel(const int* __restrict__ counts,
                                                     const int* __restrict__ bsum,
                                                     int* __restrict__ offsets,
                                                     int* __restrict__ cursor) {
    __shared__ int wsum[16];
    __shared__ int wpre[16];
    const int t = threadIdx.x, lane = t & 63, wid = t >> 6;
    int i = blockIdx.x * 1024 + t;
    int v = (i < N_NODES) ? counts[i] : 0;
    int x = v;
    #pragma unroll
    for (int off = 1; off < 64; off <<= 1) {
        int y = __shfl_up(x, off);
        if (lane >= off) x += y;
    }
    if (lane == 63) wsum[wid] = x;
    __syncthreads();
    if (t < 16) {
        int p = 0;
        for (int j = 0; j < t; ++j) p += wsum[j];
        wpre[t] = p;
    }
    __syncthreads();
    int base = bsum[blockIdx.x];
    int incl = base + x + wpre[wid];
    if (i < N_NODES) {
        offsets[i + 1] = incl;
        cursor[i]      = incl - v;
    }
    if (i == 0) offsets[0] = 0;
}

// ---------------------------------------------------------------- scatter edges into CSR order, packed {f16 w | u16 src}
__global__ void scatter_kernel(const int* __restrict__ src, const int* __restrict__ dst,
                               const float* __restrict__ w, int* __restrict__ cursor,
                               unsigned int* __restrict__ ecmp) {
    int e = blockIdx.x * blockDim.x + threadIdx.x;
    if (e < N_EDGES) {
        int d = dst[e];
        int p = atomicAdd(&cursor[d], 1);
        __half hw = __float2half(w[e]);
        ecmp[p] = ((unsigned int)__half_as_ushort(hw) << 16) | (unsigned int)src[e];
    }
}

// ---------------------------------------------------------------- pack W_hop into MFMA B-fragment order (f16)
__global__ void packW_kernel(const float* __restrict__ W, _Float16* __restrict__ Bp) {
    int i = blockIdx.x * 256 + threadIdx.x;   // 0..4095
    if (i >= 4096) return;
    int j  = i & 7;
    int l  = (i >> 3) & 63;
    int ks = (i >> 9) & 1;
    int w  = i >> 10;
    int k   = ks * 32 + ((j >> 2) * 16) + ((l >> 4) * 4) + (j & 3);
    int col = w * 16 + (l & 15);
    Bp[i] = (_Float16)W[k * 64 + col];
}

// ---------------------------------------------------------------- WlW[j] = sum_h Wl[h]*W[h,j]; blW[j] = sum_h bl[h]*W[h,j]
__global__ void wlw_kernel(const float* __restrict__ Wl, const float* __restrict__ bl,
                           const float* __restrict__ W, float* __restrict__ WlW,
                           float* __restrict__ blW) {
    int j = threadIdx.x;   // 64 threads
    float a = 0.f, b = 0.f;
    #pragma unroll 8
    for (int h = 0; h < 64; ++h) {
        float wv = W[h * 64 + j];
        a += Wl[h] * wv;
        b += bl[h] * wv;
    }
    WlW[j] = a;
    blW[j] = b;
}

// ---------------------------------------------------------------- hop-1 scalar gather: t[d,o]=sum w*nodes[s,o], u[d]=sum w
__global__ void hop1_gather_kernel(const int* __restrict__ offsets,
                                   const unsigned int* __restrict__ ecmp,
                                   const float* __restrict__ nodes,
                                   float4* __restrict__ T, float* __restrict__ U) {
    int n = blockIdx.x * blockDim.x + threadIdx.x;
    if (n >= N_NODES) return;
    int s = offsets[n], e = offsets[n + 1];
    float4 t = {0.f, 0.f, 0.f, 0.f};
    float u = 0.f;
    for (int i = s; i < e; ++i) {
        unsigned int p = ecmp[i];
        float w = __half2float(__ushort_as_half((unsigned short)(p >> 16)));
        int sn = (int)(p & 0xffffu);
        float4 nv = ((const float4*)nodes)[sn];
        t.x += w * nv.x; t.y += w * nv.y; t.z += w * nv.z; t.w += w * nv.w;
        u += w;
    }
    T[n] = t;
    U[n] = u;
}

// ---------------------------------------------------------------- hop-1 finish: X[n,o,h] = relu(t[n,o]*WlW[h] + u[n]*blW[h] + b[h])
__global__ void hop1_finish_kernel(const float4* __restrict__ T, const float* __restrict__ U,
                                   const float* __restrict__ WlW, const float* __restrict__ blW,
                                   const float* __restrict__ bias, __half* __restrict__ X) {
    int i = blockIdx.x * blockDim.x + threadIdx.x;   // 4-elem group
    const int total = N_NODES * ROW / 4;
    if (i >= total) return;
    int n   = i >> 6;
    int rem = i & 63;
    int o   = rem >> 4;
    int h4  = rem & 15;
    float t = ((const float*)&T[n])[o];
    float u = U[n];
    float4 wv = ((const float4*)WlW)[h4];
    float4 bv = ((const float4*)blW)[h4];
    float4 hv = ((const float4*)bias)[h4];
    f16x4 st;
    st[0] = (_Float16)fmaxf(t * wv.x + u * bv.x + hv.x, 0.f);
    st[1] = (_Float16)fmaxf(t * wv.y + u * bv.y + hv.y, 0.f);
    st[2] = (_Float16)fmaxf(t * wv.z + u * bv.z + hv.z, 0.f);
    st[3] = (_Float16)fmaxf(t * wv.w + u * bv.w + hv.w, 0.f);
    *(f16x4*)(X + (size_t)i * 4) = st;
}

// ---------------------------------------------------------------- fused hop (R4 structure, proven 58.6us):
// 4 waves/block, 1 dst node/wave. Edge chunk preload (4B packed) + shfl
// broadcast, 2 edges per 16B/lane load, depth-8 pipelined (w=0 padded).
// Agg parked f16 in LDS; per-wave 16x16 tile via 2x mfma_f32_16x16x32_f16.
#define ACC8(r, w)                                              \
    {                                                           \
        __half2* _h = (__half2*)&(r);                           \
        float2 _f0 = __half22float2(_h[0]);                     \
        float2 _f1 = __half22float2(_h[1]);                     \
        float2 _f2 = __half22float2(_h[2]);                     \
        float2 _f3 = __half22float2(_h[3]);                     \
        acc[0] += (w) * _f0.x; acc[1] += (w) * _f0.y;           \
        acc[2] += (w) * _f1.x; acc[3] += (w) * _f1.y;           \
        acc[4] += (w) * _f2.x; acc[5] += (w) * _f2.y;           \
        acc[6] += (w) * _f3.x; acc[7] += (w) * _f3.y;           \
    }

template<int LAST>
__global__ __launch_bounds__(256) void hop_kernel(const int* __restrict__ offsets,
                                                  const unsigned int* __restrict__ ecmp,
                                                  const __half* __restrict__ Xin,
                                                  const _Float16* __restrict__ Bp,
                                                  const float* __restrict__ bias,
                                                  __half* __restrict__ Xout,
                                                  float* __restrict__ Fout) {
    __shared__ _Float16 As16[16][72];   // 16 rows (4 nodes x 4 obs) x 64 + pad
    const int t = threadIdx.x;
    const int wid = t >> 6, lane = t & 63;
    const int half = lane >> 5;     // edge slot within a pair
    const int l32 = lane & 31;      // 16B chunk index within the 512B row
    const int node = blockIdx.x * 4 + wid;
    const int s = offsets[node], e = offsets[node + 1];

    float acc[8] = {0.f, 0.f, 0.f, 0.f, 0.f, 0.f, 0.f, 0.f};

    for (int base = s; base < e; base += 64) {
        int cnt = e - base;
        if (cnt > 64) cnt = 64;
        unsigned int pk = 0u;                 // src=0, w=+0 for pad lanes
        if (lane < cnt) pk = ecmp[base + lane];
        int pairs  = (cnt + 1) >> 1;
        int pairs8 = (pairs + 7) & ~7;        // pad to 8: extra pairs have w=0
        for (int pb = 0; pb < pairs8; pb += 8) {
            float4 r[8];
            float  w[8];
            #pragma unroll
            for (int q = 0; q < 8; ++q) {
                int sl = 2 * (pb + q) + half;
                unsigned int p = (unsigned int)__shfl((int)pk, sl);
                w[q] = __half2float(__ushort_as_half((unsigned short)(p >> 16)));
                int idx = (int)(p & 0xffffu) * ROW;
                r[q] = *(const float4*)(Xin + idx + l32 * 8);
            }
            #pragma unroll
            for (int q = 0; q < 8; ++q) ACC8(r[q], w[q]);
        }
    }

    // combine the two half-wave edge slots
    #pragma unroll
    for (int j = 0; j < 8; ++j) acc[j] += __shfl_xor(acc[j], 32);

    // park agg row as f16: element l32*8+j -> (o = l32>>3, k = (l32&7)*8 + j)
    if (half == 0) {
        int o = l32 >> 3, kb = (l32 & 7) * 8;
        __half2 p0 = __float22half2_rn(make_float2(acc[0], acc[1]));
        __half2 p1 = __float22half2_rn(make_float2(acc[2], acc[3]));
        __half2 p2 = __float22half2_rn(make_float2(acc[4], acc[5]));
        __half2 p3 = __float22half2_rn(make_float2(acc[6], acc[7]));
        float4 st;
        ((__half2*)&st)[0] = p0; ((__half2*)&st)[1] = p1;
        ((__half2*)&st)[2] = p2; ((__half2*)&st)[3] = p3;
        *(float4*)&As16[wid * 4 + o][kb] = st;
    }
    __syncthreads();

    // per-wave 16x16 output tile: rows = 16 agg rows, cols = wid*16..+15
    const int r15 = lane & 15;    // A-row for frag load; C/D col in epilogue
    const int g   = lane >> 4;    // k-group for frags; C/D row-group
    f16x8 a0, a1;
    ((f16x4*)&a0)[0] = *(const f16x4*)&As16[r15][ 0 + 4 * g];
    ((f16x4*)&a0)[1] = *(const f16x4*)&As16[r15][16 + 4 * g];
    ((f16x4*)&a1)[0] = *(const f16x4*)&As16[r15][32 + 4 * g];
    ((f16x4*)&a1)[1] = *(const f16x4*)&As16[r15][48 + 4 * g];
    f16x8 b0 = *(const f16x8*)(Bp + ((size_t)(wid * 2 + 0) * 64 + lane) * 8);
    f16x8 b1 = *(const f16x8*)(Bp + ((size_t)(wid * 2 + 1) * 64 + lane) * 8);
    f32x4 c = {0.f, 0.f, 0.f, 0.f};
    c = __builtin_amdgcn_mfma_f32_16x16x32_f16(a0, b0, c, 0, 0, 0);
    c = __builtin_amdgcn_mfma_f32_16x16x32_f16(a1, b1, c, 0, 0, 0);

    const float bv = bias[wid * 16 + r15];
    const size_t obase = (size_t)(blockIdx.x * 4 + g) * ROW + wid * 16 + r15;
    #pragma unroll
    for (int j = 0; j < 4; ++j) {           // j = obs index
        float v = fmaxf(c[j] + bv, 0.f);
        if (LAST) Fout[obase + j * 64] = v;
        else      Xout[obase + j * 64] = __float2half(v);
    }
}

// ---------------------------------------------------------------- launch
extern "C" void kernel_launch(void* const* d_in, const int* in_sizes, int n_in,
                              void* d_out, int out_size, void* d_ws, size_t ws_size,
                              hipStream_t stream) {
    const float* nodes   = (const float*)d_in[0];
    const int*   esrc    = (const int*)d_in[1];
    const int*   edst    = (const int*)d_in[2];
    const float* eweight = (const float*)d_in[3];
    const float* W_lift  = (const float*)d_in[4];
    const float* b_lift  = (const float*)d_in[5];
    const float* W_hop   = (const float*)d_in[6];
    const float* b_hop   = (const float*)d_in[7];

    char* ws = (char*)d_ws;
    __half*       X0   = (__half*)(ws);                      // 25,600,000 B
    __half*       X1   = (__half*)(ws + 25600000);           // 25,600,000 B
    unsigned int* ECMP = (unsigned int*)(ws + 51200000);     //  3,200,000 B
    int*          OFF  = (int*)(ws + 54400000);              //    200,064 B
    int*          CUR  = (int*)(ws + 54600064);              //    200,000 B
    int*          CNT  = (int*)(ws + 54800064);              //    200,000 B
    int*          BSUM = (int*)(ws + 55000064);              //        256 B
    _Float16*     BP   = (_Float16*)(ws + 55000320);         //      8,192 B
    float*        WLW  = (float*)(ws + 55008512);            //        256 B
    float*        BLW  = (float*)(ws + 55008768);            //        256 B
    float4*       T    = (float4*)(ws + 55009024);           //    800,000 B
    float*        U    = (float*)(ws + 55809024);            //    200,000 B

    // CSR build
    zero_kernel<<<(N_NODES + 255) / 256, 256, 0, stream>>>(CNT, N_NODES);
    hist_kernel<<<(N_EDGES + 255) / 256, 256, 0, stream>>>(edst, CNT);
    scan1_kernel<<<NSCAN_BLKS, 1024, 0, stream>>>(CNT, BSUM);
    scan2_kernel<<<1, 64, 0, stream>>>(BSUM);
    scan3_kernel<<<NSCAN_BLKS, 1024, 0, stream>>>(CNT, BSUM, OFF, CUR);
    scatter_kernel<<<(N_EDGES + 255) / 256, 256, 0, stream>>>(esrc, edst, eweight, CUR, ECMP);

    // weight prep
    packW_kernel<<<16, 256, 0, stream>>>(W_hop, BP);
    wlw_kernel<<<1, 64, 0, stream>>>(W_lift, b_lift, W_hop, WLW, BLW);

    // hop 1 (algebraic: scalar gather + rank-1 reconstruction) -> X0
    hop1_gather_kernel<<<(N_NODES + 255) / 256, 256, 0, stream>>>(OFF, ECMP, nodes, T, U);
    hop1_finish_kernel<<<(N_NODES * ROW / 4 + 255) / 256, 256, 0, stream>>>(T, U, WLW, BLW, b_hop, X0);

    // hops 2..5: fused gather+GEMM, double-buffered f16 X
    const int hopGrid = N_NODES / 4;   // 12500 blocks, 4 waves/block, 1 node/wave
    __half* Xi = X0;
    __half* Xo = X1;
    for (int hop = 1; hop < K_HOPS; ++hop) {
        if (hop == K_HOPS - 1) {
            hop_kernel<1><<<hopGrid, 256, 0, stream>>>(OFF, ECMP, Xi, BP, b_hop,
                                                       nullptr, (float*)d_out);
        } else {
            hop_kernel<0><<<hopGrid, 256, 0, stream>>>(OFF, ECMP, Xi, BP, b_hop,
                                                       Xo, nullptr);
        }
        __half* tmp = Xi; Xi = Xo; Xo = tmp;
    }
}

// Round 10
// 309.018 us; speedup vs baseline: 2.4133x; 1.1500x over previous
//
#include <hip/hip_runtime.h>
#include <hip/hip_fp16.h>

#define N_NODES 50000
#define N_EDGES 800000
#define N_OBS   4
#define HID     64
#define K_HOPS  5
#define ROW     (N_OBS * HID)   // 256 elements per node
#define NSCAN_BLKS ((N_NODES + 1023) / 1024)   // 49

typedef _Float16 f16x8 __attribute__((ext_vector_type(8)));
typedef _Float16 f16x4 __attribute__((ext_vector_type(4)));
typedef float    f32x4 __attribute__((ext_vector_type(4)));

// ---------------------------------------------------------------- zero
__global__ void zero_kernel(int* __restrict__ p, int n) {
    int i = blockIdx.x * blockDim.x + threadIdx.x;
    if (i < n) p[i] = 0;
}

// ---------------------------------------------------------------- histogram of dst + per-edge rank
__global__ void hist_kernel(const int* __restrict__ dst, int* __restrict__ cnt,
                            int* __restrict__ erank) {
    int e = blockIdx.x * blockDim.x + threadIdx.x;
    if (e < N_EDGES) erank[e] = atomicAdd(&cnt[dst[e]], 1);
}

// ---------------------------------------------------------------- scan pass 1: per-block sums
__global__ __launch_bounds__(1024) void scan1_kernel(const int* __restrict__ counts,
                                                     int* __restrict__ bsum) {
    __shared__ int wsum[16];
    const int t = threadIdx.x, lane = t & 63, wid = t >> 6;
    int i = blockIdx.x * 1024 + t;
    int x = (i < N_NODES) ? counts[i] : 0;
    #pragma unroll
    for (int off = 32; off > 0; off >>= 1) x += __shfl_xor(x, off);
    if (lane == 0) wsum[wid] = x;
    __syncthreads();
    if (t == 0) {
        int s = 0;
        #pragma unroll
        for (int j = 0; j < 16; ++j) s += wsum[j];
        bsum[blockIdx.x] = s;
    }
}

// ---------------------------------------------------------------- scan pass 2: exclusive scan of block sums (1 wave)
__global__ void scan2_kernel(int* __restrict__ bsum) {
    const int t = threadIdx.x;   // 64 threads
    int v = (t < NSCAN_BLKS) ? bsum[t] : 0;
    int x = v;
    #pragma unroll
    for (int off = 1; off < 64; off <<= 1) {
        int y = __shfl_up(x, off);
        if (t >= off) x += y;
    }
    if (t < NSCAN_BLKS) bsum[t] = x - v;   // exclusive
}

// ---------------------------------------------------------------- scan pass 3: full offsets
__global__ __launch_bounds__(1024) void scan3_kernel(const int* __restrict__ counts,
                                                     const int* __restrict__ bsum,
                                                     int* __restrict__ offsets) {
    __shared__ int wsum[16];
    __shared__ int wpre[16];
    const int t = threadIdx.x, lane = t & 63, wid = t >> 6;
    int i = blockIdx.x * 1024 + t;
    int v = (i < N_NODES) ? counts[i] : 0;
    int x = v;
    #pragma unroll
    for (int off = 1; off < 64; off <<= 1) {
        int y = __shfl_up(x, off);
        if (lane >= off) x += y;
    }
    if (lane == 63) wsum[wid] = x;
    __syncthreads();
    if (t < 16) {
        int p = 0;
        for (int j = 0; j < t; ++j) p += wsum[j];
        wpre[t] = p;
    }
    __syncthreads();
    int base = bsum[blockIdx.x];
    int incl = base + x + wpre[wid];
    if (i < N_NODES) offsets[i + 1] = incl;
    if (i == 0) offsets[0] = 0;
}

// ---------------------------------------------------------------- scatter edges into CSR order (atomic-free)
__global__ void scatter_kernel(const int* __restrict__ src, const int* __restrict__ dst,
                               const float* __restrict__ w, const int* __restrict__ offsets,
                               const int* __restrict__ erank,
                               unsigned int* __restrict__ ecmp) {
    int e = blockIdx.x * blockDim.x + threadIdx.x;
    if (e < N_EDGES) {
        int d = dst[e];
        int p = offsets[d] + erank[e];
        __half hw = __float2half(w[e]);
        ecmp[p] = ((unsigned int)__half_as_ushort(hw) << 16) | (unsigned int)src[e];
    }
}

// ---------------------------------------------------------------- pack W_hop into MFMA B-fragment order (f16)
__global__ void packW_kernel(const float* __restrict__ W, _Float16* __restrict__ Bp) {
    int i = blockIdx.x * 256 + threadIdx.x;   // 0..4095
    if (i >= 4096) return;
    int j  = i & 7;
    int l  = (i >> 3) & 63;
    int ks = (i >> 9) & 1;
    int w  = i >> 10;
    int k   = ks * 32 + ((j >> 2) * 16) + ((l >> 4) * 4) + (j & 3);
    int col = w * 16 + (l & 15);
    Bp[i] = (_Float16)W[k * 64 + col];
}

// ---------------------------------------------------------------- WlW[j] = sum_h Wl[h]*W[h,j]; blW[j] = sum_h bl[h]*W[h,j]
__global__ void wlw_kernel(const float* __restrict__ Wl, const float* __restrict__ bl,
                           const float* __restrict__ W, float* __restrict__ WlW,
                           float* __restrict__ blW) {
    int j = threadIdx.x;   // 64 threads
    float a = 0.f, b = 0.f;
    #pragma unroll 8
    for (int h = 0; h < 64; ++h) {
        float wv = W[h * 64 + j];
        a += Wl[h] * wv;
        b += bl[h] * wv;
    }
    WlW[j] = a;
    blW[j] = b;
}

// ---------------------------------------------------------------- hop-1 scalar gather: t[d,o]=sum w*nodes[s,o], u[d]=sum w
__global__ void hop1_gather_kernel(const int* __restrict__ offsets,
                                   const unsigned int* __restrict__ ecmp,
                                   const float* __restrict__ nodes,
                                   float4* __restrict__ T, float* __restrict__ U) {
    int n = blockIdx.x * blockDim.x + threadIdx.x;
    if (n >= N_NODES) return;
    int s = offsets[n], e = offsets[n + 1];
    float4 t = {0.f, 0.f, 0.f, 0.f};
    float u = 0.f;
    for (int i = s; i < e; ++i) {
        unsigned int p = ecmp[i];
        float w = __half2float(__ushort_as_half((unsigned short)(p >> 16)));
        int sn = (int)(p & 0xffffu);
        float4 nv = ((const float4*)nodes)[sn];
        t.x += w * nv.x; t.y += w * nv.y; t.z += w * nv.z; t.w += w * nv.w;
        u += w;
    }
    T[n] = t;
    U[n] = u;
}

// ---------------------------------------------------------------- hop-1 finish: X[n,o,h] = relu(t[n,o]*WlW[h] + u[n]*blW[h] + b[h])
__global__ void hop1_finish_kernel(const float4* __restrict__ T, const float* __restrict__ U,
                                   const float* __restrict__ WlW, const float* __restrict__ blW,
                                   const float* __restrict__ bias, __half* __restrict__ X) {
    int i = blockIdx.x * blockDim.x + threadIdx.x;   // 4-elem group
    const int total = N_NODES * ROW / 4;
    if (i >= total) return;
    int n   = i >> 6;
    int rem = i & 63;
    int o   = rem >> 4;
    int h4  = rem & 15;
    float t = ((const float*)&T[n])[o];
    float u = U[n];
    float4 wv = ((const float4*)WlW)[h4];
    float4 bv = ((const float4*)blW)[h4];
    float4 hv = ((const float4*)bias)[h4];
    f16x4 st;
    st[0] = (_Float16)fmaxf(t * wv.x + u * bv.x + hv.x, 0.f);
    st[1] = (_Float16)fmaxf(t * wv.y + u * bv.y + hv.y, 0.f);
    st[2] = (_Float16)fmaxf(t * wv.z + u * bv.z + hv.z, 0.f);
    st[3] = (_Float16)fmaxf(t * wv.w + u * bv.w + hv.w, 0.f);
    *(f16x4*)(X + (size_t)i * 4) = st;
}

// ---------------------------------------------------------------- fused hop (R4 structure + pk_fma_f16 accumulation):
// 4 waves/block, 1 dst node/wave. Edge chunk preload (4B packed) + shfl
// broadcast, 2 edges per 16B/lane load, depth-8 pipelined (w=0 padded).
// Accumulate in f16 (v_pk_fma_f16, 2 accumulators); park agg in LDS via
// one b128 store; per-wave 16x16 tile via 2x mfma_f32_16x16x32_f16.
template<int LAST>
__global__ __launch_bounds__(256) void hop_kernel(const int* __restrict__ offsets,
                                                  const unsigned int* __restrict__ ecmp,
                                                  const __half* __restrict__ Xin,
                                                  const _Float16* __restrict__ Bp,
                                                  const float* __restrict__ bias,
                                                  __half* __restrict__ Xout,
                                                  float* __restrict__ Fout) {
    __shared__ _Float16 As16[16][72];   // 16 rows (4 nodes x 4 obs) x 64 + pad
    const int t = threadIdx.x;
    const int wid = t >> 6, lane = t & 63;
    const int half = lane >> 5;     // edge slot within a pair
    const int l32 = lane & 31;      // 16B chunk index within the 512B row
    const int node = blockIdx.x * 4 + wid;
    const int s = offsets[node], e = offsets[node + 1];
    const _Float16* __restrict__ X16 = (const _Float16*)Xin;

    f16x8 acc0 = (f16x8)(_Float16)0.0f;
    f16x8 acc1 = (f16x8)(_Float16)0.0f;

    for (int base = s; base < e; base += 64) {
        int cnt = e - base;
        if (cnt > 64) cnt = 64;
        unsigned int pk = 0u;                 // src=0, w=+0 for pad lanes
        if (lane < cnt) pk = ecmp[base + lane];
        int pairs  = (cnt + 1) >> 1;
        int pairs8 = (pairs + 7) & ~7;        // pad to 8: extra pairs have w=0
        for (int pb = 0; pb < pairs8; pb += 8) {
            f16x8 r[8];
            _Float16 wh[8];
            #pragma unroll
            for (int q = 0; q < 8; ++q) {
                int sl = 2 * (pb + q) + half;
                unsigned int p = (unsigned int)__shfl((int)pk, sl);
                unsigned short wu = (unsigned short)(p >> 16);
                wh[q] = __builtin_bit_cast(_Float16, wu);
                int idx = (int)(p & 0xffffu) * ROW;
                r[q] = *(const f16x8*)(X16 + idx + l32 * 8);
            }
            #pragma unroll
            for (int q = 0; q < 8; q += 2) {
                acc0 += r[q]     * wh[q];
                acc1 += r[q + 1] * wh[q + 1];
            }
        }
    }
    acc0 += acc1;

    // combine the two half-wave edge slots (4 int shfls + pk-add)
    int4 ai = *(int4*)&acc0;
    int4 bi;
    bi.x = __shfl_xor(ai.x, 32);
    bi.y = __shfl_xor(ai.y, 32);
    bi.z = __shfl_xor(ai.z, 32);
    bi.w = __shfl_xor(ai.w, 32);
    acc0 += *(f16x8*)&bi;

    // park agg row: lane l32 holds elements l32*8..+7 -> (o = l32>>3, kb = (l32&7)*8)
    if (half == 0) {
        int o = l32 >> 3, kb = (l32 & 7) * 8;
        *(f16x8*)&As16[wid * 4 + o][kb] = acc0;
    }
    __syncthreads();

    // per-wave 16x16 output tile: rows = 16 agg rows, cols = wid*16..+15
    const int r15 = lane & 15;    // A-row for frag load; C/D col in epilogue
    const int g   = lane >> 4;    // k-group for frags; C/D row-group
    f16x8 a0, a1;
    ((f16x4*)&a0)[0] = *(const f16x4*)&As16[r15][ 0 + 4 * g];
    ((f16x4*)&a0)[1] = *(const f16x4*)&As16[r15][16 + 4 * g];
    ((f16x4*)&a1)[0] = *(const f16x4*)&As16[r15][32 + 4 * g];
    ((f16x4*)&a1)[1] = *(const f16x4*)&As16[r15][48 + 4 * g];
    f16x8 b0 = *(const f16x8*)(Bp + ((size_t)(wid * 2 + 0) * 64 + lane) * 8);
    f16x8 b1 = *(const f16x8*)(Bp + ((size_t)(wid * 2 + 1) * 64 + lane) * 8);
    f32x4 c = {0.f, 0.f, 0.f, 0.f};
    c = __builtin_amdgcn_mfma_f32_16x16x32_f16(a0, b0, c, 0, 0, 0);
    c = __builtin_amdgcn_mfma_f32_16x16x32_f16(a1, b1, c, 0, 0, 0);

    const float bv = bias[wid * 16 + r15];
    const size_t obase = (size_t)(blockIdx.x * 4 + g) * ROW + wid * 16 + r15;
    #pragma unroll
    for (int j = 0; j < 4; ++j) {           // j = obs index
        float v = fmaxf(c[j] + bv, 0.f);
        if (LAST) Fout[obase + j * 64] = v;
        else      Xout[obase + j * 64] = __float2half(v);
    }
}

// ---------------------------------------------------------------- launch
extern "C" void kernel_launch(void* const* d_in, const int* in_sizes, int n_in,
                              void* d_out, int out_size, void* d_ws, size_t ws_size,
                              hipStream_t stream) {
    const float* nodes   = (const float*)d_in[0];
    const int*   esrc    = (const int*)d_in[1];
    const int*   edst    = (const int*)d_in[2];
    const float* eweight = (const float*)d_in[3];
    const float* W_lift  = (const float*)d_in[4];
    const float* b_lift  = (const float*)d_in[5];
    const float* W_hop   = (const float*)d_in[6];
    const float* b_hop   = (const float*)d_in[7];

    char* ws = (char*)d_ws;
    __half*       X0   = (__half*)(ws);                      // 25,600,000 B
    __half*       X1   = (__half*)(ws + 25600000);           // 25,600,000 B
    unsigned int* ECMP = (unsigned int*)(ws + 51200000);     //  3,200,000 B
    int*          OFF  = (int*)(ws + 54400000);              //    200,064 B
    int*          CNT  = (int*)(ws + 54600064);              //    200,000 B
    int*          BSUM = (int*)(ws + 54800064);              //        256 B
    _Float16*     BP   = (_Float16*)(ws + 54800320);         //      8,192 B
    float*        WLW  = (float*)(ws + 54808512);            //        256 B
    float*        BLW  = (float*)(ws + 54808768);            //        256 B
    // ERANK overlays T/U (disjoint lifetimes: ERANK dead after scatter)
    int*          ERANK = (int*)(ws + 54809024);             //  3,200,000 B -> end 58,009,024
    float4*       T    = (float4*)(ws + 54809024);           //    800,000 B
    float*        U    = (float*)(ws + 55609024);            //    200,000 B

    // CSR build: hist computes per-edge rank; scatter is atomic-free
    zero_kernel<<<(N_NODES + 255) / 256, 256, 0, stream>>>(CNT, N_NODES);
    hist_kernel<<<(N_EDGES + 255) / 256, 256, 0, stream>>>(edst, CNT, ERANK);
    scan1_kernel<<<NSCAN_BLKS, 1024, 0, stream>>>(CNT, BSUM);
    scan2_kernel<<<1, 64, 0, stream>>>(BSUM);
    scan3_kernel<<<NSCAN_BLKS, 1024, 0, stream>>>(CNT, BSUM, OFF);
    scatter_kernel<<<(N_EDGES + 255) / 256, 256, 0, stream>>>(esrc, edst, eweight, OFF, ERANK, ECMP);

    // weight prep
    packW_kernel<<<16, 256, 0, stream>>>(W_hop, BP);
    wlw_kernel<<<1, 64, 0, stream>>>(W_lift, b_lift, W_hop, WLW, BLW);

    // hop 1 (algebraic: scalar gather + rank-1 reconstruction) -> X0
    hop1_gather_kernel<<<(N_NODES + 255) / 256, 256, 0, stream>>>(OFF, ECMP, nodes, T, U);
    hop1_finish_kernel<<<(N_NODES * ROW / 4 + 255) / 256, 256, 0, stream>>>(T, U, WLW, BLW, b_hop, X0);

    // hops 2..5: fused gather+GEMM, double-buffered f16 X
    const int hopGrid = N_NODES / 4;   // 12500 blocks, 4 waves/block, 1 node/wave
    __half* Xi = X0;
    __half* Xo = X1;
    for (int hop = 1; hop < K_HOPS; ++hop) {
        if (hop == K_HOPS - 1) {
            hop_kernel<1><<<hopGrid, 256, 0, stream>>>(OFF, ECMP, Xi, BP, b_hop,
                                                       nullptr, (float*)d_out);
        } else {
            hop_kernel<0><<<hopGrid, 256, 0, stream>>>(OFF, ECMP, Xi, BP, b_hop,
                                                       Xo, nullptr);
        }
        __half* tmp = Xi; Xi = Xo; Xo = tmp;
    }
}